// Round 3
// baseline (241.721 us; speedup 1.0000x reference)
//
#include <hip/hip_runtime.h>
#include <math.h>

// Problem constants
#define BB   512   // batch
#define TT   256   // timesteps
#define CNNC 512   // channels
#define VV   37    // vocab
#define HH   8     // hidden
#define G4   32    // 4*H
#define CH   8     // scan chunk length (timesteps)
#define NCH  (TT / CH)      // 32 chunks
#define CHW  (CH * 256)     // words per chunk of one 8-seq group (8 KB)

#define L2E 1.4426950408889634f

// native vector types for vector loads/stores (HIP float4 is a class type)
typedef float f4_t __attribute__((ext_vector_type(4)));

// DPP cross-lane mov: pure VALU latency. quad_perm 0xB1=xor1, 0x4E=xor2,
// 0x1B=xor3; 0x141=row_half_mirror (xor7 within each 8-lane half-row).
template <int CTRL>
__device__ __forceinline__ float dpp_f(float x) {
    int r = __builtin_amdgcn_update_dpp(0, __float_as_int(x), CTRL, 0xF, 0xF, true);
    return __int_as_float(r);
}

__device__ __forceinline__ float rcp_f(float x) { return __builtin_amdgcn_rcpf(x); }
__device__ __forceinline__ float exp2_f(float x) { return __builtin_amdgcn_exp2f(x); }

// ---------------------------------------------------------------------------
// Kernel 1: avg-pool(features) @ W_in.T partial -> featp[quarter][B][V]
// (unchanged: BW-bound on the 51 MB feature read, at roofline)
// ---------------------------------------------------------------------------
__global__ __launch_bounds__(256) void k_feat(const float* __restrict__ features,
                                              const float* __restrict__ W_in,
                                              const float* __restrict__ b_in,
                                              float* __restrict__ featp) {
    __shared__ __align__(16) float raw[128 * 49];    // 25088 B
    __shared__ float pooled[128];
    const int b = blockIdx.x, qt = blockIdx.y, tid = threadIdx.x;
    const f4_t* src =
        (const f4_t*)(features + (size_t)b * CNNC * 49 + qt * (128 * 49));
    f4_t* dst = (f4_t*)raw;
    for (int i = tid; i < 128 * 49 / 4; i += 256)
        dst[i] = __builtin_nontemporal_load(&src[i]);
    __syncthreads();
    if (tid < 128) {
        const float* p = raw + tid * 49;
        float s = 0.f;
        #pragma unroll
        for (int i = 0; i < 49; ++i) s += p[i];
        pooled[tid] = s;
    }
    __syncthreads();
    const int v = tid >> 2, pp = tid & 3;
    if (v < VV) {
        const float* w = W_in + v * CNNC + qt * 128 + pp * 32;
        const float* q = pooled + pp * 32;
        float s = 0.f;
        #pragma unroll
        for (int i = 0; i < 32; ++i) s += q[i] * w[i];
        s += __shfl_xor(s, 1);
        s += __shfl_xor(s, 2);
        if (pp == 0)
            featp[(qt * BB + b) * VV + v] =
                s * (1.f / 49.f) + (qt == 0 ? b_in[v] : 0.f);
    }
}

// ---------------------------------------------------------------------------
// Kernel 2: xproj = -(x_t @ W_ih.T + b_ih + b_hh) * scale_g, GATE-FUSED layout.
// Per t, a 64-seq... wait: groups of 8 seqs share one 256-word row:
//   word = (s8*8 + j)*4 + gate   (gate 0..3 = i,f,g,o ; j = gg&7)
// so a scan lane (s8,j) reads its 4 gate pre-activations as ONE f4.
// This block (bg, tile) covers seqs 4bg..4bg+3 = group bg>>1, half bg&1.
// ---------------------------------------------------------------------------
#define CAPS 1188   // per-seq caption stage stride (1184+4)
#define SOS  132    // out-stage stride per t (128+4)
__global__ __launch_bounds__(256) void k_xproj(const float* __restrict__ captions,
                                               const float* __restrict__ W_ih,
                                               const float* __restrict__ b_ih,
                                               const float* __restrict__ b_hh,
                                               const float* __restrict__ featp,
                                               float* __restrict__ xproj) {
    __shared__ float W[G4 * VV];                     // 4736 B
    __shared__ float bias[G4];
    __shared__ float cap[4 * CAPS];                  // 19008 B
    __shared__ __align__(16) float so[32 * SOS];     // 16896 B
    const int bg = blockIdx.x, tile = blockIdx.y;
    const int tid = threadIdx.x;
    for (int i = tid; i < G4 * VV; i += 256) W[i] = W_ih[i];
    if (tid < G4) bias[tid] = b_ih[tid] + b_hh[tid];

    // stage caption rows [start, start+32) for the block's 4 sequences
    const int t0 = tile * 32;
    const int start = (tile == 0) ? 0 : t0 - 1;
    for (int i = tid; i < 4 * 1184; i += 256) {
        const int s2 = i / 1184;                      // const-div -> mul/shift
        const int off = i - s2 * 1184;
        cap[s2 * CAPS + off] = __builtin_nontemporal_load(
            &captions[((size_t)(bg * 4 + s2) * TT + start) * VV + off]);
    }
    __syncthreads();

    const int tl = tid >> 3;             // 0..31 local t
    const int s  = (tid >> 1) & 3;       // seq within block
    const int r  = tid & 1;              // gate half (0: rows 0-15, 1: 16-31)
    const int b  = bg * 4 + s;

    float xr[VV];
    if (tile == 0 && tl == 0) {
        #pragma unroll
        for (int v = 0; v < VV; ++v)
            xr[v] = featp[b * VV + v] + featp[(BB + b) * VV + v] +
                    featp[(2 * BB + b) * VV + v] + featp[(3 * BB + b) * VV + v];
    } else {
        const int lr = (tile == 0) ? tl - 1 : tl;
        const float* x = &cap[s * CAPS + lr * VV];
        #pragma unroll
        for (int v = 0; v < VV; ++v) xr[v] = x[v];
    }

    const int g0 = r * 16;
    float acc[16];
    #pragma unroll
    for (int g = 0; g < 16; ++g) acc[g] = bias[g0 + g];
    #pragma unroll
    for (int v = 0; v < VV; ++v) {
        const float xv = xr[v];
        #pragma unroll
        for (int g = 0; g < 16; ++g) acc[g] += xv * W[(g0 + g) * VV + v];
    }
    #pragma unroll
    for (int g = 0; g < 16; ++g) {
        const int gg   = g0 + g;
        const int gate = gg >> 3;                 // 0:i 1:f 2:g 3:o
        const int j    = gg & 7;
        const float sc = (gate == 2) ? (-2.f * L2E) : (-L2E);
        const int word = s * 32 + j * 4 + gate;   // local (4-seq) word 0..127
        so[tl * SOS + word] = acc[g] * sc;
    }
    __syncthreads();

    // write the 16 KB tile: group row = 256 words/t, this block fills half
    float* chunk = xproj + ((size_t)(bg >> 1) * TT + t0) * 256 + (bg & 1) * 128;
    for (int i = tid; i < 1024; i += 256) {
        const int t2 = i >> 5, rest = i & 31;
        f4_t val = *(const f4_t*)&so[t2 * SOS + rest * 4];
        *(f4_t*)&chunk[t2 * 256 + rest * 4] = val;
    }
}

// ---------------------------------------------------------------------------
// Kernel 3 (FUSED): sequential scan + output softmax, gate-fused lanes.
//   wave 0 (tid 0-63): 8 lanes/seq, 8 seqs. Each lane computes ALL FOUR gates
//     for its j: no cross-lane exchange on the c-path, DPP broadcast depth 2.
//     Pre-activations arrive as one f4 per lane per t (global->VGPR, double-
//     buffered per chunk). h flushed to padded LDS once per chunk.
//   wave 1 (tid 64-127): one chunk behind; each lane owns one (seq,t) row:
//     37-logit dot + softmax -> LDS stage (stride 37, conflict-free) ->
//     dense coalesced f4 nontemporal stores (NOT per-lane scalar scatter).
// Sync: raw s_barrier + lgkmcnt(0) only (no vmcnt drain).
// ---------------------------------------------------------------------------
#define TSTR 12                 // hst per-t dword stride (8 data + 4 pad)
#define SSTR (CH * TSTR + 4)    // 100: per (buffer,seq) stride

#define STEP(cur, tl) do {                                                  \
    const float pI = cur[tl].x, pF = cur[tl].y;                             \
    const float pG = cur[tl].z, pO = cur[tl].w;                             \
    const float ha0 = h;                                                    \
    const float ha1 = dpp_f<0xB1>(h);                                       \
    const float ha2 = dpp_f<0x4E>(h);                                       \
    const float ha3 = dpp_f<0x1B>(h);                                       \
    const float ha7 = dpp_f<0x141>(h);                                      \
    const float ha4 = dpp_f<0x1B>(ha7);                                     \
    const float ha5 = dpp_f<0x4E>(ha7);                                     \
    const float ha6 = dpp_f<0xB1>(ha7);                                     \
    float iA = fmaf(wI[0], ha0, pI);                                        \
    iA = fmaf(wI[1], ha1, iA); iA = fmaf(wI[2], ha2, iA);                   \
    iA = fmaf(wI[3], ha3, iA);                                              \
    float iB = wI[4] * ha4;                                                 \
    iB = fmaf(wI[5], ha5, iB); iB = fmaf(wI[6], ha6, iB);                   \
    iB = fmaf(wI[7], ha7, iB);                                              \
    const float npI = iA + iB;                                              \
    float fA = fmaf(wF[0], ha0, pF);                                        \
    fA = fmaf(wF[1], ha1, fA); fA = fmaf(wF[2], ha2, fA);                   \
    fA = fmaf(wF[3], ha3, fA);                                              \
    float fB = wF[4] * ha4;                                                 \
    fB = fmaf(wF[5], ha5, fB); fB = fmaf(wF[6], ha6, fB);                   \
    fB = fmaf(wF[7], ha7, fB);                                              \
    const float npF = fA + fB;                                              \
    float gA = fmaf(wG[0], ha0, pG);                                        \
    gA = fmaf(wG[1], ha1, gA); gA = fmaf(wG[2], ha2, gA);                   \
    gA = fmaf(wG[3], ha3, gA);                                              \
    float gB = wG[4] * ha4;                                                 \
    gB = fmaf(wG[5], ha5, gB); gB = fmaf(wG[6], ha6, gB);                   \
    gB = fmaf(wG[7], ha7, gB);                                              \
    const float npG = gA + gB;                                              \
    float oA = fmaf(wO[0], ha0, pO);                                        \
    oA = fmaf(wO[1], ha1, oA); oA = fmaf(wO[2], ha2, oA);                   \
    oA = fmaf(wO[3], ha3, oA);                                              \
    float oB = wO[4] * ha4;                                                 \
    oB = fmaf(wO[5], ha5, oB); oB = fmaf(wO[6], ha6, oB);                   \
    oB = fmaf(wO[7], ha7, oB);                                              \
    const float npO = oA + oB;                                              \
    const float gi = rcp_f(1.f + exp2_f(npI));    /* sigmoid(i) */          \
    const float gf = rcp_f(1.f + exp2_f(npF));    /* sigmoid(f) */          \
    const float uG = rcp_f(1.f + exp2_f(npG));    /* sigmoid(2*pre_g) */    \
    const float go = rcp_f(1.f + exp2_f(npO));    /* sigmoid(o) */          \
    const float gg = fmaf(-4.f * L2E, uG, 2.f * L2E); /* -2L2E*tanh(g) */   \
    const float ig = gi * gg;                                               \
    c = fmaf(gf, c, ig);                          /* c holds -2L2E*c_true */\
    const float rv = rcp_f(1.f + exp2_f(c));                                \
    h = fmaf(go + go, rv, -go);                   /* o*(2rv-1)=o*tanh(c) */ \
    hsv[tl] = h;                                                            \
} while (0)

#define CHUNK(cur, nxt, it, pbuf) do {                                      \
    if ((it) + 1 < NCH) {                                                   \
        const f4_t* src = (const f4_t*)(xp + (size_t)((it) + 1) * CHW);     \
        _Pragma("unroll")                                                   \
        for (int tl = 0; tl < CH; ++tl) nxt[tl] = src[tl * 64 + lane];      \
        __builtin_amdgcn_sched_barrier(0);                                  \
    }                                                                       \
    _Pragma("unroll")                                                       \
    for (int tl = 0; tl < CH; ++tl) STEP(cur, tl);                          \
    {                                                                       \
        float* hb = &hst[((pbuf) * 8 + s8) * SSTR + j];                     \
        _Pragma("unroll")                                                   \
        for (int i = 0; i < CH; ++i) hb[i * TSTR] = hsv[i];                 \
    }                                                                       \
} while (0)

#define EMIT(pk) do {                                                       \
    const int os = lane >> 3, otl = lane & 7;                               \
    const float* hp = &hst[(((pk) & 1) * 8 + os) * SSTR + otl * TSTR];      \
    const f4_t h0 = *(const f4_t*)hp;                                       \
    const f4_t h1 = *(const f4_t*)(hp + 4);                                 \
    const f4_t* W4 = (const f4_t*)Wo;                                       \
    float z[VV];                                                            \
    float m = -1e30f;                                                       \
    _Pragma("unroll")                                                       \
    for (int v = 0; v < VV; ++v) {                                          \
        const f4_t w0 = W4[v * 2], w1 = W4[v * 2 + 1];                      \
        float sv = bo[v];                                                   \
        sv = fmaf(h0.x, w0.x, sv); sv = fmaf(h0.y, w0.y, sv);               \
        sv = fmaf(h0.z, w0.z, sv); sv = fmaf(h0.w, w0.w, sv);               \
        sv = fmaf(h1.x, w1.x, sv); sv = fmaf(h1.y, w1.y, sv);               \
        sv = fmaf(h1.z, w1.z, sv); sv = fmaf(h1.w, w1.w, sv);               \
        z[v] = sv;                                                          \
        m = fmaxf(m, sv);                                                   \
    }                                                                       \
    float sum = 0.f;                                                        \
    _Pragma("unroll")                                                       \
    for (int v = 0; v < VV; ++v) {                                          \
        z[v] = exp2_f((z[v] - m) * L2E);                                    \
        sum += z[v];                                                        \
    }                                                                       \
    const float rs = rcp_f(sum);                                            \
    _Pragma("unroll")                                                       \
    for (int v = 0; v < VV; ++v) zst[lane * VV + v] = z[v] * rs;            \
    /* same-wave LDS write->read; compiler inserts lgkmcnt */               \
    _Pragma("unroll")                                                       \
    for (int sq = 0; sq < 8; ++sq) {                                        \
        const f4_t* sp = (const f4_t*)&zst[sq * (CH * VV)];                 \
        f4_t* gp = (f4_t*)(out + ((size_t)(bg * 8 + sq) * TT + (pk) * CH) * VV); \
        for (int k2 = lane; k2 < CH * VV / 4; k2 += 64)                     \
            __builtin_nontemporal_store(sp[k2], &gp[k2]);                   \
    }                                                                       \
} while (0)

__global__ __launch_bounds__(128) void k_lstm(const float* __restrict__ W_hh,
                                              const float* __restrict__ xproj,
                                              const float* __restrict__ W_out,
                                              const float* __restrict__ b_out,
                                              float* __restrict__ out) {
    __shared__ __align__(16) float hst[2 * 8 * SSTR];     // 6400 B
    __shared__ __align__(16) float zst[8 * CH * VV];      // 9472 B
    __shared__ __align__(16) float Wo[VV * HH];
    __shared__ float bo[VV];

    const int tid  = threadIdx.x;
    const int wv   = tid >> 6;        // 0: scan; 1: output
    const int lane = tid & 63;
    const int bg   = blockIdx.x;      // 0..63 (8-seq groups)
    const float* xp = xproj + (size_t)bg * (TT * 256);

    // scan-wave lane decode: lane = s8*8 + j
    const int s8 = lane >> 3;
    const int j  = lane & 7;

    f4_t cA[CH], cB[CH];
    float hsv[CH];
    float wI[HH], wF[HH], wG[HH], wO[HH];

    if (wv == 0) {
        #pragma unroll
        for (int m = 0; m < HH; ++m) {
            wI[m] = -L2E        * W_hh[(     j) * HH + (j ^ m)];
            wF[m] = -L2E        * W_hh[( 8 + j) * HH + (j ^ m)];
            wG[m] = -2.f * L2E  * W_hh[(16 + j) * HH + (j ^ m)];
            wO[m] = -L2E        * W_hh[(24 + j) * HH + (j ^ m)];
        }
        // prefetch chunk 0 into cA
        const f4_t* src = (const f4_t*)xp;
        #pragma unroll
        for (int tl = 0; tl < CH; ++tl) cA[tl] = src[tl * 64 + lane];
    } else {
        for (int i = lane; i < VV * HH; i += 64) Wo[i] = W_out[i];
        if (lane < VV) bo[lane] = b_out[lane];
    }

    float h = 0.f, c = 0.f;

    // 34 slots (17 outer x 2), slots 0..32 active: wave0 computes chunk `it`
    // (it<32), wave1 emits chunk `it-1` (1<=it<=32). Uniform barriers.
    for (int ou = 0; ou < 17; ++ou) {
        {
            const int it = ou * 2;
            if (wv == 0) {
                if (it < NCH) CHUNK(cA, cB, it, 0);
            } else if (it >= 1 && it <= NCH) {
                EMIT(it - 1);
            }
            asm volatile("s_waitcnt lgkmcnt(0)" ::: "memory");
            __builtin_amdgcn_s_barrier();
            __builtin_amdgcn_sched_barrier(0);
        }
        {
            const int it = ou * 2 + 1;
            if (it <= NCH) {
                if (wv == 0) {
                    if (it < NCH) CHUNK(cB, cA, it, 1);
                } else {
                    EMIT(it - 1);
                }
                asm volatile("s_waitcnt lgkmcnt(0)" ::: "memory");
                __builtin_amdgcn_s_barrier();
                __builtin_amdgcn_sched_barrier(0);
            }
        }
    }
}

// ---------------------------------------------------------------------------
// Workspace (floats): featp@0 (4*512*37=75,776) | xproj@81920 (4,194,304)
// ---------------------------------------------------------------------------
extern "C" void kernel_launch(void* const* d_in, const int* in_sizes, int n_in,
                              void* d_out, int out_size, void* d_ws, size_t ws_size,
                              hipStream_t stream) {
    const float* features = (const float*)d_in[0];
    const float* captions = (const float*)d_in[1];
    const float* W_in     = (const float*)d_in[2];
    const float* b_in     = (const float*)d_in[3];
    const float* W_ih     = (const float*)d_in[4];
    const float* W_hh     = (const float*)d_in[5];
    const float* b_ih     = (const float*)d_in[6];
    const float* b_hh     = (const float*)d_in[7];
    const float* W_out    = (const float*)d_in[8];
    const float* b_out    = (const float*)d_in[9];
    float* out = (float*)d_out;

    float* ws    = (float*)d_ws;
    float* featp = ws;
    float* xproj = ws + 81920;

    k_feat <<<dim3(BB, 4),  256, 0, stream>>>(features, W_in, b_in, featp);
    k_xproj<<<dim3(128, 8), 256, 0, stream>>>(captions, W_ih, b_ih, b_hh, featp, xproj);
    k_lstm <<<64,           128, 0, stream>>>(W_hh, xproj, W_out, b_out, out);
}

// Round 4
// 192.613 us; speedup vs baseline: 1.2550x; 1.2550x over previous
//
#include <hip/hip_runtime.h>
#include <math.h>

// Problem constants
#define BB   512   // batch
#define TT   256   // timesteps
#define CNNC 512   // channels
#define VV   37    // vocab
#define HH   8     // hidden
#define G4   32    // 4*H
#define CH   16    // scan chunk length (timesteps)
#define NCH  (TT / CH)      // 16 chunks
#define CHW  (CH * 128)     // words per chunk of one 4-seq group (8 KB)

#define L2E 1.4426950408889634f

// native vector types for vector loads/stores (HIP float4 is a class type)
typedef float f4_t __attribute__((ext_vector_type(4)));
typedef float f2_t __attribute__((ext_vector_type(2)));

// DPP cross-lane mov: pure VALU latency. quad_perm 0xB1=xor1, 0x4E=xor2,
// 0x1B=xor3; 0x141=row_half_mirror (xor7); 0x140=row_mirror (xor15).
template <int CTRL>
__device__ __forceinline__ float dpp_f(float x) {
    int r = __builtin_amdgcn_update_dpp(0, __float_as_int(x), CTRL, 0xF, 0xF, true);
    return __int_as_float(r);
}

__device__ __forceinline__ float rcp_f(float x) { return __builtin_amdgcn_rcpf(x); }
__device__ __forceinline__ float exp2_f(float x) { return __builtin_amdgcn_exp2f(x); }

// packed dual-FP32 helpers: compile to v_pk_fma_f32 / v_pk_mul_f32 / v_pk_add_f32
__device__ __forceinline__ f2_t fma2(f2_t a, f2_t b, f2_t c) {
    return __builtin_elementwise_fma(a, b, c);
}
__device__ __forceinline__ f2_t sp2(float x) { f2_t v = {x, x}; return v; }

// ---------------------------------------------------------------------------
// Kernel 1: avg-pool(features) @ W_in.T partial -> featp[quarter][B][V]
// (unchanged: BW-bound on the 51 MB feature read, at roofline)
// ---------------------------------------------------------------------------
__global__ __launch_bounds__(256) void k_feat(const float* __restrict__ features,
                                              const float* __restrict__ W_in,
                                              const float* __restrict__ b_in,
                                              float* __restrict__ featp) {
    __shared__ __align__(16) float raw[128 * 49];    // 25088 B
    __shared__ float pooled[128];
    const int b = blockIdx.x, qt = blockIdx.y, tid = threadIdx.x;
    const f4_t* src =
        (const f4_t*)(features + (size_t)b * CNNC * 49 + qt * (128 * 49));
    f4_t* dst = (f4_t*)raw;
    for (int i = tid; i < 128 * 49 / 4; i += 256)
        dst[i] = __builtin_nontemporal_load(&src[i]);
    __syncthreads();
    if (tid < 128) {
        const float* p = raw + tid * 49;
        float s = 0.f;
        #pragma unroll
        for (int i = 0; i < 49; ++i) s += p[i];
        pooled[tid] = s;
    }
    __syncthreads();
    const int v = tid >> 2, pp = tid & 3;
    if (v < VV) {
        const float* w = W_in + v * CNNC + qt * 128 + pp * 32;
        const float* q = pooled + pp * 32;
        float s = 0.f;
        #pragma unroll
        for (int i = 0; i < 32; ++i) s += q[i] * w[i];
        s += __shfl_xor(s, 1);
        s += __shfl_xor(s, 2);
        if (pp == 0)
            featp[(qt * BB + b) * VV + v] =
                s * (1.f / 49.f) + (qt == 0 ? b_in[v] : 0.f);
    }
}

// ---------------------------------------------------------------------------
// Kernel 2: xproj = -(x_t @ W_ih.T + b_ih + b_hh) * scale_g, pre-permuted.
// Word layout per t (128 words): word = ((gg&15)*4 + s4)*2 + (gg>>4)
// so that a scan lane's (A-row, B-row) pre-activations are ADJACENT ->
// one coalesced global_load_dwordx2 per lane per timestep in k_lstm.
// ---------------------------------------------------------------------------
#define CAPS 1188   // per-seq caption stage stride (1184+4)
#define SOS  132    // out-stage stride per t (128+4)
__global__ __launch_bounds__(256) void k_xproj(const float* __restrict__ captions,
                                               const float* __restrict__ W_ih,
                                               const float* __restrict__ b_ih,
                                               const float* __restrict__ b_hh,
                                               const float* __restrict__ featp,
                                               float* __restrict__ xproj) {
    __shared__ float W[G4 * VV];                     // 4736 B
    __shared__ float bias[G4];
    __shared__ float cap[4 * CAPS];                  // 19008 B
    __shared__ __align__(16) float so[32 * SOS];     // 16896 B
    const int bg = blockIdx.x, tile = blockIdx.y;
    const int tid = threadIdx.x;
    for (int i = tid; i < G4 * VV; i += 256) W[i] = W_ih[i];
    if (tid < G4) bias[tid] = b_ih[tid] + b_hh[tid];

    // stage caption rows [start, start+32) for the block's 4 sequences
    const int t0 = tile * 32;
    const int start = (tile == 0) ? 0 : t0 - 1;
    for (int i = tid; i < 4 * 1184; i += 256) {
        const int s2 = i / 1184;                      // const-div -> mul/shift
        const int off = i - s2 * 1184;
        cap[s2 * CAPS + off] = __builtin_nontemporal_load(
            &captions[((size_t)(bg * 4 + s2) * TT + start) * VV + off]);
    }
    __syncthreads();

    const int tl = tid >> 3;             // 0..31 local t
    const int s  = (tid >> 1) & 3;       // seq within block
    const int r  = tid & 1;              // gate half (0: rows 0-15, 1: 16-31)
    const int b  = bg * 4 + s;

    float xr[VV];
    if (tile == 0 && tl == 0) {
        #pragma unroll
        for (int v = 0; v < VV; ++v)
            xr[v] = featp[b * VV + v] + featp[(BB + b) * VV + v] +
                    featp[(2 * BB + b) * VV + v] + featp[(3 * BB + b) * VV + v];
    } else {
        const int lr = (tile == 0) ? tl - 1 : tl;
        const float* x = &cap[s * CAPS + lr * VV];
        #pragma unroll
        for (int v = 0; v < VV; ++v) xr[v] = x[v];
    }

    const int g0 = r * 16;
    float acc[16];
    #pragma unroll
    for (int g = 0; g < 16; ++g) acc[g] = bias[g0 + g];
    #pragma unroll
    for (int v = 0; v < VV; ++v) {
        const float xv = xr[v];
        #pragma unroll
        for (int g = 0; g < 16; ++g) acc[g] += xv * W[(g0 + g) * VV + v];
    }
    #pragma unroll
    for (int g = 0; g < 16; ++g) {
        const int gg = g0 + g;
        const float sc = (gg >= 16 && gg < 24) ? (-2.f * L2E) : (-L2E);
        const int word = ((gg & 15) * 4 + s) * 2 + (gg >> 4);  // pair layout
        so[tl * SOS + word] = acc[g] * sc;
    }
    __syncthreads();

    // write the 16 KB tile [t][word] contiguously
    float* chunk = xproj + ((size_t)bg * TT + t0) * 128;
    for (int i = tid; i < 1024; i += 256) {
        const int t2 = i >> 5, rest = i & 31;
        f4_t val = *(const f4_t*)&so[t2 * SOS + rest * 4];
        *(f4_t*)&chunk[t2 * 128 + rest * 4] = val;
    }
}

// ---------------------------------------------------------------------------
// Kernel 3 (FUSED): sequential scan + output softmax  [R2 structure].
//   wave 0 (tid 0-63):  16 lanes/sequence scan, global->VGPR double-buffered
//     staging, zero memory ops in the 16-step inner loop. NEW: the two
//     length-8 gate dots are PACKED dual-FP32 (v_pk_fma_f32): w2[m] holds
//     (wA[m], wB[m]); 16 FMA + 2 add -> 8 pk_fma + 1 pk_add, cutting the
//     serial instruction stream ~38 -> ~29 per step (the scan wave is
//     latency-bound in-order: measured ~10-13 cyc/instruction R2 vs R3).
//   wave 1 (tid 64-127): one chunk behind; each lane owns one (seq,t) row:
//     37-logit dot + softmax + store to out.
// Sync: raw s_barrier + lgkmcnt(0) only (no vmcnt drain).
// ---------------------------------------------------------------------------
#define TSTR 12                 // hst per-t dword stride (8 data + 4 pad)
#define SSTR (CH * TSTR + 4)    // 196: per (buffer,seq) stride

#define STEP(cur, tl) do {                                                  \
    const f2_t p2 = cur[tl];                                                \
    const float ha0 = h;                                                    \
    const float ha1 = dpp_f<0x4E>(h);                                       \
    const float ha3 = dpp_f<0x141>(h);                                      \
    const float ha2 = dpp_f<0x4E>(ha3);                                     \
    const float ha7 = dpp_f<0x140>(h);                                      \
    const float ha4 = dpp_f<0x141>(ha7);                                    \
    const float ha5 = dpp_f<0x4E>(ha4);                                     \
    const float ha6 = dpp_f<0x1B>(ha7);                                     \
    f2_t acc0 = fma2(w2[0], sp2(ha0), p2);                                  \
    acc0 = fma2(w2[1], sp2(ha1), acc0);                                     \
    acc0 = fma2(w2[2], sp2(ha2), acc0);                                     \
    acc0 = fma2(w2[3], sp2(ha3), acc0);                                     \
    f2_t acc1 = w2[4] * sp2(ha4);                                           \
    acc1 = fma2(w2[5], sp2(ha5), acc1);                                     \
    acc1 = fma2(w2[6], sp2(ha6), acc1);                                     \
    acc1 = fma2(w2[7], sp2(ha7), acc1);                                     \
    const f2_t np2 = acc0 + acc1;                                           \
    const float eA = rcp_f(1.f + exp2_f(np2.x));  /* r=0: i ; r=1: f */     \
    const float uB = rcp_f(1.f + exp2_f(np2.y));  /* r=0: raw g ; r=1: o */ \
    const float gg = fmaf(-4.f * L2E, uB, 2.f * L2E); /* -2L2E*tanh(g) */   \
    const float myU = r ? eA : eA * gg;           /* r=0: -2L2E*i*g; r=1: f */\
    const float otU = dpp_f<0xB1>(myU);                                     \
    const float fg  = r ? myU : otU;                                        \
    const float igg = r ? otU : myU;                                        \
    const float ogx = dpp_f<0xB1>(uB);                                      \
    const float og  = r ? uB : ogx;                                         \
    c = fmaf(fg, c, igg);                         /* c holds -2L2E*c_true */\
    const float rv = rcp_f(1.f + exp2_f(c));                                \
    h = fmaf(og + og, rv, -og);                   /* og*(2rv-1) */          \
    hsv[tl] = h;                                                            \
} while (0)

#define CHUNK(cur, nxt, it, pbuf) do {                                      \
    if ((it) + 1 < NCH) {                                                   \
        const f2_t* src = (const f2_t*)(xp + ((it) + 1) * CHW + roff2);     \
        _Pragma("unroll")                                                   \
        for (int tl = 0; tl < CH; ++tl) nxt[tl] = src[tl * 64];             \
        __builtin_amdgcn_sched_barrier(0);                                  \
    }                                                                       \
    _Pragma("unroll")                                                       \
    for (int tl = 0; tl < CH; ++tl) STEP(cur, tl);                          \
    if (r == 0) {                                                           \
        float* hb = &hst[((pbuf) * 4 + s4) * SSTR + j];                     \
        _Pragma("unroll")                                                   \
        for (int i = 0; i < CH; ++i) hb[i * TSTR] = hsv[i];                 \
    }                                                                       \
} while (0)

#define EMIT(pk) do {                                                       \
    const int os = lane >> 4, otl = lane & 15;                              \
    const float* hp = &hst[(((pk) & 1) * 4 + os) * SSTR + otl * TSTR];      \
    const f4_t h0 = *(const f4_t*)hp;                                       \
    const f4_t h1 = *(const f4_t*)(hp + 4);                                 \
    const f4_t* W4 = (const f4_t*)Wo;                                       \
    float z[VV];                                                            \
    float m = -1e30f;                                                       \
    _Pragma("unroll")                                                       \
    for (int v = 0; v < VV; ++v) {                                          \
        const f4_t w0 = W4[v * 2], w1 = W4[v * 2 + 1];                      \
        float sv = bo[v];                                                   \
        sv = fmaf(h0.x, w0.x, sv); sv = fmaf(h0.y, w0.y, sv);               \
        sv = fmaf(h0.z, w0.z, sv); sv = fmaf(h0.w, w0.w, sv);               \
        sv = fmaf(h1.x, w1.x, sv); sv = fmaf(h1.y, w1.y, sv);               \
        sv = fmaf(h1.z, w1.z, sv); sv = fmaf(h1.w, w1.w, sv);               \
        z[v] = sv;                                                          \
        m = fmaxf(m, sv);                                                   \
    }                                                                       \
    float sum = 0.f;                                                        \
    _Pragma("unroll")                                                       \
    for (int v = 0; v < VV; ++v) {                                          \
        z[v] = exp2_f((z[v] - m) * L2E);                                    \
        sum += z[v];                                                        \
    }                                                                       \
    const float rs = rcp_f(sum);                                            \
    const int ob = bg * 4 + os;                                             \
    const int ot = (pk) * CH + otl;                                         \
    float* op = out + ((size_t)ob * TT + ot) * VV;                          \
    _Pragma("unroll")                                                       \
    for (int v = 0; v < VV; ++v) op[v] = z[v] * rs;                         \
} while (0)

__global__ __launch_bounds__(128) void k_lstm(const float* __restrict__ W_hh,
                                              const float* __restrict__ xproj,
                                              const float* __restrict__ W_out,
                                              const float* __restrict__ b_out,
                                              float* __restrict__ out) {
    __shared__ __align__(16) float hst[2 * 4 * SSTR];   // 6272 B
    __shared__ __align__(16) float Wo[VV * HH];
    __shared__ float bo[VV];

    const int tid  = threadIdx.x;
    const int wv   = tid >> 6;        // 0: scan; 1: output
    const int lane = tid & 63;
    const int bg   = blockIdx.x;      // 0..127
    const float* xp = xproj + (size_t)bg * (TT * 128);

    // scan-wave lane decode
    const int s4 = lane >> 4;
    const int q  = lane & 15;
    const int j  = q >> 1;
    const int r  = q & 1;
    const int rowA  = r * 8 + j;                 // i or f row
    const int roff2 = (rowA * 4 + s4) * 2;       // word offset of (A,B) pair

    f2_t cA[CH], cB[CH];
    float hsv[CH];
    f2_t w2[HH];                                 // packed (wA, wB)

    if (wv == 0) {
        const int rowB = 16 + rowA;              // g or o row
        const float scA = -L2E;
        const float scB = r ? -L2E : (-2.f * L2E);
        #pragma unroll
        for (int m = 0; m < HH; ++m) {
            f2_t wp = {scA * W_hh[rowA * HH + (j ^ m)],
                       scB * W_hh[rowB * HH + (j ^ m)]};
            w2[m] = wp;
        }
        // prefetch chunk 0 into cA
        const f2_t* src = (const f2_t*)(xp + roff2);
        #pragma unroll
        for (int tl = 0; tl < CH; ++tl) cA[tl] = src[tl * 64];
    } else {
        for (int i = lane; i < VV * HH; i += 64) Wo[i] = W_out[i];
        if (lane < VV) bo[lane] = b_out[lane];
    }

    float h = 0.f, c = 0.f;

    // 18 slots (9 outer x 2), slots 0..16 active: wave0 computes chunk `it`
    // (it<16), wave1 emits chunk `it-1` (1<=it<=16). 17 barriers, uniform.
    for (int ou = 0; ou < 9; ++ou) {
        {
            const int it = ou * 2;
            if (wv == 0) {
                if (it < NCH) CHUNK(cA, cB, it, 0);
            } else if (it >= 1 && it <= NCH) {
                EMIT(it - 1);
            }
            asm volatile("s_waitcnt lgkmcnt(0)" ::: "memory");
            __builtin_amdgcn_s_barrier();
            __builtin_amdgcn_sched_barrier(0);
        }
        {
            const int it = ou * 2 + 1;
            if (it <= NCH) {
                if (wv == 0) {
                    if (it < NCH) CHUNK(cB, cA, it, 1);
                } else {
                    EMIT(it - 1);
                }
                asm volatile("s_waitcnt lgkmcnt(0)" ::: "memory");
                __builtin_amdgcn_s_barrier();
                __builtin_amdgcn_sched_barrier(0);
            }
        }
    }
}

// ---------------------------------------------------------------------------
// Workspace (floats): featp@0 (4*512*37=75,776) | xproj@81920 (4,194,304)
// ---------------------------------------------------------------------------
extern "C" void kernel_launch(void* const* d_in, const int* in_sizes, int n_in,
                              void* d_out, int out_size, void* d_ws, size_t ws_size,
                              hipStream_t stream) {
    const float* features = (const float*)d_in[0];
    const float* captions = (const float*)d_in[1];
    const float* W_in     = (const float*)d_in[2];
    const float* b_in     = (const float*)d_in[3];
    const float* W_ih     = (const float*)d_in[4];
    const float* W_hh     = (const float*)d_in[5];
    const float* b_ih     = (const float*)d_in[6];
    const float* b_hh     = (const float*)d_in[7];
    const float* W_out    = (const float*)d_in[8];
    const float* b_out    = (const float*)d_in[9];
    float* out = (float*)d_out;

    float* ws    = (float*)d_ws;
    float* featp = ws;
    float* xproj = ws + 81920;

    k_feat <<<dim3(BB, 4),  256, 0, stream>>>(features, W_in, b_in, featp);
    k_xproj<<<dim3(128, 8), 256, 0, stream>>>(captions, W_ih, b_ih, b_hh, featp, xproj);
    k_lstm <<<128,          128, 0, stream>>>(W_hh, xproj, W_out, b_out, out);
}